// Round 1
// 204.807 us; speedup vs baseline: 1.0294x; 1.0294x over previous
//
#include <hip/hip_runtime.h>
#include <hip/hip_bf16.h>
#include <math.h>
#include <stdint.h>

#define BDIM 2
#define NDIM 512
#define HID 768
#define BIAF 256
#define CLS 14
#define DD 257   // BIAF+1
#define NPOS 30
#define SDIM 25
#define HSZ 539  // 2*257+25
#define PK 288   // padded contraction length (i and j), 9*32
#define PJ 384   // packW j-rows padding

typedef unsigned short ushort_t;
typedef __attribute__((ext_vector_type(8))) short short8;   // 8 bf16
typedef __attribute__((ext_vector_type(4))) float floatx4;  // 4 f32
typedef __attribute__((ext_vector_type(4))) unsigned short ushort4_t;

#define MFMA16(a, b, c) __builtin_amdgcn_mfma_f32_16x16x32_bf16((a), (b), (c), 0, 0, 0)

__device__ inline float bf2f(ushort_t u) {
    union { unsigned int i; float f; } c; c.i = ((unsigned)u) << 16; return c.f;
}
__device__ inline ushort_t f2bf(float f) {
    __hip_bfloat16 h = __float2bfloat16(f);
    return *(ushort_t*)&h;
}

// async global->LDS, 16B per lane. LDS dest = wave-uniform base + lane*16.
__device__ inline void glds16(const ushort_t* g, const ushort_t* l) {
    __builtin_amdgcn_global_load_lds(
        (const __attribute__((address_space(1))) unsigned int*)(unsigned long long)(uintptr_t)g,
        (__attribute__((address_space(3))) unsigned int*)(unsigned int)(uintptr_t)l,
        16, 0, 0);
}

// ---------------------------------------------------------------------------
// LDS swizzle (T2-style, rule #21 compliant: linear LDS dest, pre-swizzled
// global source, swizzled read address).
// Tile stored as [R][32] bf16 (64B rows). View row-pairs as 128B super-rows
// with eight 16B slots; slot' = slot ^ (super_row & 7).  8-lane read groups
// then cover all 32 banks (conflict-free b128).
// ---------------------------------------------------------------------------

// ---------------------------------------------------------------------------
// repack_t: packW[k][j][i] = bf16(biafW[k][i][j]), zero-padded to PJ x PK
// ---------------------------------------------------------------------------
__global__ __launch_bounds__(256) void repack_t(
    const float* __restrict__ biafW, ushort_t* __restrict__ packW)
{
    __shared__ float tile[32][33];
    const int i0 = blockIdx.x * 32;
    const int j0 = blockIdx.y * 32;
    const int k  = blockIdx.z;
    const int r8 = threadIdx.x >> 5;   // 0..7
    const int c  = threadIdx.x & 31;
    #pragma unroll
    for (int rr = 0; rr < 4; ++rr) {
        int r = rr * 8 + r8;
        int gi = i0 + r, gj = j0 + c;
        tile[r][c] = (gi < DD && gj < DD) ? biafW[((size_t)k * DD + gi) * DD + gj] : 0.f;
    }
    __syncthreads();
    #pragma unroll
    for (int rr = 0; rr < 4; ++rr) {
        int jr = rr * 8 + r8;
        packW[((size_t)k * PJ + (j0 + jr)) * PK + i0 + c] = f2bf(tile[c][jr]);
    }
}

// ---------------------------------------------------------------------------
// prep_split: fused wsplit + xysplit + fill_pads (float4-vectorized splits).
// thread sections: [0,196608) weights x4 | [196608,589824) x/y x4 | pads.
// grid = 2816 blocks x 256.
// ---------------------------------------------------------------------------
__global__ __launch_bounds__(256) void prep_split(
    const float* __restrict__ x, const float* __restrict__ y,
    const float* __restrict__ m1w, const float* __restrict__ m2w,
    const float* __restrict__ hw,  const float* __restrict__ tw,
    ushort_t* __restrict__ xhi, ushort_t* __restrict__ xlo,
    ushort_t* __restrict__ yhi, ushort_t* __restrict__ ylo,
    ushort_t* __restrict__ whi, ushort_t* __restrict__ wlo,
    ushort_t* __restrict__ h1hi, ushort_t* __restrict__ h1lo,
    ushort_t* __restrict__ t1hi, ushort_t* __restrict__ t1lo)
{
    int tg = blockIdx.x * 256 + threadIdx.x;
    if (tg < 196608) {
        // weights: 4 matrices x 196608 elems, 4 elems/thread
        int mat = tg / 49152;
        int e0  = (tg % 49152) * 4;
        const float* src = (mat == 0) ? m1w : (mat == 1) ? m2w : (mat == 2) ? hw : tw;
        float4 v = *(const float4*)(src + e0);
        size_t o = (size_t)mat * 196608 + e0;
        ushort4_t h, lo;
        h[0] = f2bf(v.x); lo[0] = f2bf(v.x - bf2f(h[0]));
        h[1] = f2bf(v.y); lo[1] = f2bf(v.y - bf2f(h[1]));
        h[2] = f2bf(v.z); lo[2] = f2bf(v.z - bf2f(h[2]));
        h[3] = f2bf(v.w); lo[3] = f2bf(v.w - bf2f(h[3]));
        *(ushort4_t*)(whi + o) = h;
        *(ushort4_t*)(wlo + o) = lo;
    } else if (tg < 589824) {
        // x and y: 786432 elems each, 4 elems/thread
        int t = tg - 196608;
        int which = t / 196608;
        int e0 = (t % 196608) * 4;
        const float* src = which ? y : x;
        float4 v = *(const float4*)(src + e0);
        ushort4_t h, lo;
        h[0] = f2bf(v.x); lo[0] = f2bf(v.x - bf2f(h[0]));
        h[1] = f2bf(v.y); lo[1] = f2bf(v.y - bf2f(h[1]));
        h[2] = f2bf(v.z); lo[2] = f2bf(v.z - bf2f(h[2]));
        h[3] = f2bf(v.w); lo[3] = f2bf(v.w - bf2f(h[3]));
        *(ushort4_t*)((which ? yhi : xhi) + e0) = h;
        *(ushort4_t*)((which ? ylo : xlo) + e0) = lo;
    } else {
        // pad columns of h1/t1 planes: col 256 = 1.0(hi)/0(lo), 257..287 = 0
        int idx = tg - 589824;                 // 0..131071
        int plane = idx >> 15;                 // 0..3
        int tok = (idx >> 5) & 1023;
        int c   = 256 + (idx & 31);
        ushort_t* dst = (plane == 0) ? h1hi : (plane == 1) ? h1lo : (plane == 2) ? t1hi : t1lo;
        ushort_t val = (c == 256 && (plane == 0 || plane == 2)) ? (ushort_t)0x3F80 : (ushort_t)0;
        dst[(size_t)tok * PK + c] = val;
    }
}

// ---------------------------------------------------------------------------
// proj_mfma v3: direct-load MFMA, pre-split operands, 3-term.
// grid (8 ft, 16 mt, 4 proj); wave tile = 16 tokens x 32 features.
// ---------------------------------------------------------------------------
__global__ __launch_bounds__(256) void proj_mfma(
    const ushort_t* __restrict__ xhi, const ushort_t* __restrict__ xlo,
    const ushort_t* __restrict__ yhi, const ushort_t* __restrict__ ylo,
    const ushort_t* __restrict__ whi, const ushort_t* __restrict__ wlo,
    const float* __restrict__ m1b, const float* __restrict__ m2b,
    const float* __restrict__ hb,  const float* __restrict__ tb,
    ushort_t* __restrict__ h1hi, ushort_t* __restrict__ h1lo,
    ushort_t* __restrict__ t1hi, ushort_t* __restrict__ t1lo,
    float* __restrict__ headf, float* __restrict__ tailf)
{
    const int ft = blockIdx.x;       // 0..7  -> 32 features
    const int mt = blockIdx.y;       // 0..15 -> 64 tokens
    const int proj = blockIdx.z;     // 0..3
    const int wave = threadIdx.x >> 6, L = threadIdx.x & 63;
    const int quad = L >> 4, l16 = L & 15;
    const int tok0 = mt * 64 + wave * 16;
    const int f0 = ft * 32;

    const ushort_t* ahi_p = (proj == 1) ? yhi : xhi;
    const ushort_t* alo_p = (proj == 1) ? ylo : xlo;
    const float* bias = (proj == 0) ? m1b : (proj == 1) ? m2b : (proj == 2) ? hb : tb;

    const size_t aoff = (size_t)(tok0 + l16) * HID + quad * 8;
    const size_t wbase = (size_t)proj * BIAF * HID;
    const size_t b0 = wbase + (size_t)(f0 + l16) * HID + quad * 8;
    const size_t b1 = wbase + (size_t)(f0 + 16 + l16) * HID + quad * 8;

    floatx4 acc0 = {0.f, 0.f, 0.f, 0.f}, acc1 = {0.f, 0.f, 0.f, 0.f};
    #pragma unroll 4
    for (int k0 = 0; k0 < HID; k0 += 32) {
        short8 ah  = *(const short8*)(ahi_p + aoff + k0);
        short8 al  = *(const short8*)(alo_p + aoff + k0);
        short8 bh0 = *(const short8*)(whi + b0 + k0);
        short8 bl0 = *(const short8*)(wlo + b0 + k0);
        short8 bh1 = *(const short8*)(whi + b1 + k0);
        short8 bl1 = *(const short8*)(wlo + b1 + k0);
        acc0 = MFMA16(ah, bh0, acc0);
        acc1 = MFMA16(ah, bh1, acc1);
        acc0 = MFMA16(al, bh0, acc0);
        acc1 = MFMA16(al, bh1, acc1);
        acc0 = MFMA16(ah, bl0, acc0);
        acc1 = MFMA16(ah, bl1, acc1);
    }

    #pragma unroll
    for (int nf = 0; nf < 2; ++nf) {
        floatx4 a = nf ? acc1 : acc0;
        int feat = f0 + nf * 16 + l16;
        float bv = bias[feat];
        #pragma unroll
        for (int r = 0; r < 4; ++r) {
            int tok = tok0 + quad * 4 + r;
            float v = a[r] + bv;
            if (proj <= 1) {
                float g = 0.5f * v * (1.0f + erff(v * 0.70710678118654752f));
                ushort_t h = f2bf(g);
                ushort_t lo = f2bf(g - bf2f(h));
                if (proj == 0) { h1hi[(size_t)tok * PK + feat] = h; h1lo[(size_t)tok * PK + feat] = lo; }
                else           { t1hi[(size_t)tok * PK + feat] = h; t1lo[(size_t)tok * PK + feat] = lo; }
            } else {
                float lv = (v >= 0.f) ? v : 0.01f * v;
                if (proj == 2) headf[(size_t)tok * 256 + feat] = lv;
                else           tailf[(size_t)tok * 256 + feat] = lv;
            }
        }
    }
}

// ---------------------------------------------------------------------------
// hk_tk_sk: fused.  blocks 0..127: hk/tk.  blocks 128..129: sk.
// hk[b][k][m] = dot(headf[tok], Wh[k]) + Wh[k][256]; tk likewise with Wt
// sk[k][d] = sum_h size_emb[d][h] * Ws[k][h]
// ---------------------------------------------------------------------------
__global__ __launch_bounds__(256) void hk_tk_sk(
    const float* __restrict__ headf, const float* __restrict__ tailf,
    const float* __restrict__ W, const float* __restrict__ semb,
    float* __restrict__ hk, float* __restrict__ tk, float* __restrict__ skp)
{
    if (blockIdx.x >= 128) {
        int idx = (blockIdx.x - 128) * 256 + threadIdx.x;
        if (idx < CLS * NPOS) {
            int k = idx / NPOS, d = idx % NPOS;
            float acc = 0.f;
            for (int h = 0; h < SDIM; ++h)
                acc += semb[d*SDIM + h] * W[k*HSZ + 2*DD + h];
            skp[idx] = acc;
        }
        return;
    }
    int p = blockIdx.x * 256 + threadIdx.x;  // 32768 items
    int which = p >> 14;                     // 0=hk, 1=tk
    int idx = p & 16383;
    int tok = idx >> 4;
    int k = idx & 15;
    if (k >= CLS) return;
    const float* row = (which ? tailf : headf) + (size_t)tok * 256;
    const float* wr = W + (size_t)k * HSZ + (which ? DD : 0);
    float acc = 0.f;
    for (int f4 = 0; f4 < 64; ++f4) {
        float4 rv = *(const float4*)(row + f4 * 4);
        acc += rv.x * wr[f4*4] + rv.y * wr[f4*4+1] + rv.z * wr[f4*4+2] + rv.w * wr[f4*4+3];
    }
    acc += wr[256];
    float* dst = which ? tk : hk;
    dst[(size_t)(tok >> 9) * CLS * NDIM + (size_t)k * NDIM + (tok & 511)] = acc;
}

// ---------------------------------------------------------------------------
// mb_tile v4: A[bk][m][j] = sum_i h1[b][m][i] * biafW[k][i][j]  (2-term on h1)
// tile 64x96, glds staging with XOR-swizzled LDS (conflict-free b128 reads).
// grid (3 jt, 8 mt, 28 bk) = 672 blocks.
// ---------------------------------------------------------------------------
__global__ __launch_bounds__(256) void mb_tile(
    const ushort_t* __restrict__ h1hi, const ushort_t* __restrict__ h1lo,
    const ushort_t* __restrict__ packW,
    ushort_t* __restrict__ Ab)
{
    __shared__ ushort_t Ah[64 * 32];   // 4KB
    __shared__ ushort_t Al[64 * 32];   // 4KB
    __shared__ ushort_t Bt[96 * 32];   // 6KB
    const int jt = blockIdx.x, mt = blockIdx.y, bk = blockIdx.z;
    const int b = bk / CLS, k = bk % CLS;
    const int tid = threadIdx.x;
    const int wave = tid >> 6, L = tid & 63;
    const int quad = L >> 4, l16 = L & 15;
    // staging: lane L's linear LDS slot (sr=L>>3, sl=L&7) receives global
    // slot u = sl ^ sr  ->  global row 2*sr+(u>>2), col-quad u&3
    const int sr = L >> 3, u = (L & 7) ^ sr;
    const int srow = 2 * sr + (u >> 2);        // row within 16-row segment
    const int scol = (u & 3) * 8;              // element col within 32
    // read: fragment (row=base16+l16, quad) lives at swizzled slot
    const int rbase = (l16 >> 1) * 64 + ((((((l16 & 1) << 2) | quad)) ^ (l16 >> 1)) * 8);
    const int m0 = mt * 64, j0 = jt * 96;
    const int wm = (wave >> 1) * 32, wj = (wave & 1) * 48;

    const ushort_t* gAh = h1hi + (size_t)(b * NDIM + m0) * PK;
    const ushort_t* gAl = h1lo + (size_t)(b * NDIM + m0) * PK;
    const ushort_t* gB  = packW + ((size_t)k * PJ + j0) * PK;

    floatx4 acc[2][3];
    #pragma unroll
    for (int mi = 0; mi < 2; ++mi)
        #pragma unroll
        for (int ni = 0; ni < 3; ++ni)
            #pragma unroll
            for (int r = 0; r < 4; ++r) acc[mi][ni][r] = 0.f;

    for (int k0 = 0; k0 < PK; k0 += 32) {
        // 14 x 1KB segments: 4 Ah, 4 Al, 6 Bt
        for (int s = wave; s < 14; s += 4) {
            const ushort_t* g; const ushort_t* l;
            if (s < 4)      { l = Ah + s * 512;       g = gAh + (size_t)(s * 16 + srow) * PK + k0 + scol; }
            else if (s < 8) { l = Al + (s - 4) * 512; g = gAl + (size_t)((s - 4) * 16 + srow) * PK + k0 + scol; }
            else            { l = Bt + (s - 8) * 512; g = gB  + (size_t)((s - 8) * 16 + srow) * PK + k0 + scol; }
            glds16(g, l);
        }
        __syncthreads();
        short8 ah[2], al[2], bb[3];
        #pragma unroll
        for (int mi = 0; mi < 2; ++mi) {
            ah[mi] = *(const short8*)(Ah + (wm + mi * 16) * 32 + rbase);
            al[mi] = *(const short8*)(Al + (wm + mi * 16) * 32 + rbase);
        }
        #pragma unroll
        for (int ni = 0; ni < 3; ++ni)
            bb[ni] = *(const short8*)(Bt + (wj + ni * 16) * 32 + rbase);
        #pragma unroll
        for (int mi = 0; mi < 2; ++mi)
            #pragma unroll
            for (int ni = 0; ni < 3; ++ni) {
                acc[mi][ni] = MFMA16(ah[mi], bb[ni], acc[mi][ni]);
                acc[mi][ni] = MFMA16(al[mi], bb[ni], acc[mi][ni]);
            }
        __syncthreads();
    }

    ushort_t* Aout = Ab + (size_t)bk * NDIM * PK;
    #pragma unroll
    for (int mi = 0; mi < 2; ++mi) {
        #pragma unroll
        for (int r = 0; r < 4; ++r) {
            int row = m0 + wm + mi * 16 + quad * 4 + r;
            #pragma unroll
            for (int ni = 0; ni < 3; ++ni) {
                int col = j0 + wj + ni * 16 + l16;
                Aout[(size_t)row * PK + col] = f2bf(acc[mi][ni][r]);
            }
        }
    }
}

// ---------------------------------------------------------------------------
// mo_tile v4: out[bk][m][n] = sum_j A[bk][m][j]*t1[b][n][j] + hk + tk + sk
// tile 64x128, glds staging with XOR-swizzled LDS (conflict-free b128 reads).
// grid (4 nt, 8 mt, 28 bk) = 896 blocks.
// ---------------------------------------------------------------------------
__global__ __launch_bounds__(256) void mo_tile(
    const ushort_t* __restrict__ Ab,
    const ushort_t* __restrict__ t1hi, const ushort_t* __restrict__ t1lo,
    const float* __restrict__ hk, const float* __restrict__ tk,
    const float* __restrict__ sk,
    float* __restrict__ out)
{
    __shared__ ushort_t At[64 * 32];    // 4KB
    __shared__ ushort_t Bh[128 * 32];   // 8KB
    __shared__ ushort_t Bl[128 * 32];   // 8KB
    __shared__ float skr[NPOS];
    const int nt = blockIdx.x, mt = blockIdx.y, bk = blockIdx.z;
    const int b = bk / CLS, k = bk % CLS;
    const int tid = threadIdx.x;
    if (tid < NPOS) skr[tid] = sk[k * NPOS + tid];
    const int wave = tid >> 6, L = tid & 63;
    const int quad = L >> 4, l16 = L & 15;
    const int sr = L >> 3, u = (L & 7) ^ sr;
    const int srow = 2 * sr + (u >> 2);
    const int scol = (u & 3) * 8;
    const int rbase = (l16 >> 1) * 64 + ((((((l16 & 1) << 2) | quad)) ^ (l16 >> 1)) * 8);
    const int m0 = mt * 64, n0 = nt * 128;
    const int wm = (wave >> 1) * 32, wn = (wave & 1) * 64;

    const ushort_t* gA  = Ab + ((size_t)bk * NDIM + m0) * PK;
    const ushort_t* gBh = t1hi + (size_t)(b * NDIM + n0) * PK;
    const ushort_t* gBl = t1lo + (size_t)(b * NDIM + n0) * PK;

    floatx4 acc[2][4];
    #pragma unroll
    for (int mi = 0; mi < 2; ++mi)
        #pragma unroll
        for (int ni = 0; ni < 4; ++ni)
            #pragma unroll
            for (int r = 0; r < 4; ++r) acc[mi][ni][r] = 0.f;

    for (int k0 = 0; k0 < PK; k0 += 32) {
        // 20 x 1KB segments: 4 At, 8 Bh, 8 Bl
        for (int s = wave; s < 20; s += 4) {
            const ushort_t* g; const ushort_t* l;
            if (s < 4)       { l = At + s * 512;        g = gA  + (size_t)(s * 16 + srow) * PK + k0 + scol; }
            else if (s < 12) { l = Bh + (s - 4) * 512;  g = gBh + (size_t)((s - 4) * 16 + srow) * PK + k0 + scol; }
            else             { l = Bl + (s - 12) * 512; g = gBl + (size_t)((s - 12) * 16 + srow) * PK + k0 + scol; }
            glds16(g, l);
        }
        __syncthreads();
        short8 a[2], bh[4], bl[4];
        #pragma unroll
        for (int mi = 0; mi < 2; ++mi)
            a[mi] = *(const short8*)(At + (wm + mi * 16) * 32 + rbase);
        #pragma unroll
        for (int ni = 0; ni < 4; ++ni) {
            bh[ni] = *(const short8*)(Bh + (wn + ni * 16) * 32 + rbase);
            bl[ni] = *(const short8*)(Bl + (wn + ni * 16) * 32 + rbase);
        }
        #pragma unroll
        for (int mi = 0; mi < 2; ++mi)
            #pragma unroll
            for (int ni = 0; ni < 4; ++ni) {
                acc[mi][ni] = MFMA16(a[mi], bh[ni], acc[mi][ni]);
                acc[mi][ni] = MFMA16(a[mi], bl[ni], acc[mi][ni]);
            }
        __syncthreads();
    }

    const size_t obase = (size_t)bk * NDIM;
    #pragma unroll
    for (int mi = 0; mi < 2; ++mi) {
        #pragma unroll
        for (int r = 0; r < 4; ++r) {
            int row = m0 + wm + mi * 16 + quad * 4 + r;
            float hv = hk[obase + row];
            #pragma unroll
            for (int ni = 0; ni < 4; ++ni) {
                int col = n0 + wn + ni * 16 + l16;
                int d = col - row; d = d < -15 ? -15 : (d > 14 ? 14 : d); d += 15;
                out[(obase + row) * NDIM + col] = acc[mi][ni][r] + hv + tk[obase + col] + skr[d];
            }
        }
    }
}

// ---------------------------------------------------------------------------
extern "C" void kernel_launch(void* const* d_in, const int* in_sizes, int n_in,
                              void* d_out, int out_size, void* d_ws, size_t ws_size,
                              hipStream_t stream) {
    const float* x    = (const float*)d_in[0];
    const float* y    = (const float*)d_in[1];
    // d_in[2] = z : unused
    const float* m1w  = (const float*)d_in[3];
    const float* m1b  = (const float*)d_in[4];
    const float* m2w  = (const float*)d_in[5];
    const float* m2b  = (const float*)d_in[6];
    const float* hw   = (const float*)d_in[7];
    const float* hb   = (const float*)d_in[8];
    const float* tw   = (const float*)d_in[9];
    const float* tb   = (const float*)d_in[10];
    const float* biafW= (const float*)d_in[11];
    const float* W    = (const float*)d_in[12];
    const float* semb = (const float*)d_in[13];

    char* p = (char*)d_ws;
    float* hk   = (float*)p;                    p += 57344;
    float* tk   = (float*)p;                    p += 57344;
    float* skp  = (float*)p;                    p += 2048;
    float* headf= (float*)p;                    p += 1048576;
    float* tailf= (float*)p;                    p += 1048576;
    ushort_t* h1hi = (ushort_t*)p;              p += 589824;
    ushort_t* h1lo = (ushort_t*)p;              p += 589824;
    ushort_t* t1hi = (ushort_t*)p;              p += 589824;
    ushort_t* t1lo = (ushort_t*)p;              p += 589824;
    ushort_t* packW= (ushort_t*)p;              p += 3096576;  // 14*384*288*2
    ushort_t* whi  = (ushort_t*)p;              p += 1572864;  // 4*256*768*2
    ushort_t* wlo  = (ushort_t*)p;              p += 1572864;
    ushort_t* Abuf = (ushort_t*)p;              p += 8257536;  // 28*512*288*2
    ushort_t* xhi  = (ushort_t*)p;              p += 1572864;  // 1024*768*2
    ushort_t* xlo  = (ushort_t*)p;              p += 1572864;
    ushort_t* yhi  = (ushort_t*)p;              p += 1572864;
    ushort_t* ylo  = (ushort_t*)p;              p += 1572864;

    repack_t<<<dim3(9, 12, CLS), 256, 0, stream>>>(biafW, packW);
    prep_split<<<2816, 256, 0, stream>>>(x, y, m1w, m2w, hw, tw,
                                         xhi, xlo, yhi, ylo, whi, wlo,
                                         h1hi, h1lo, t1hi, t1lo);
    proj_mfma<<<dim3(8, 16, 4), 256, 0, stream>>>(xhi, xlo, yhi, ylo, whi, wlo,
                                                  m1b, m2b, hb, tb,
                                                  h1hi, h1lo, t1hi, t1lo, headf, tailf);
    hk_tk_sk<<<130, 256, 0, stream>>>(headf, tailf, W, semb, hk, tk, skp);
    mb_tile<<<dim3(3, 8, BDIM*CLS), 256, 0, stream>>>(h1hi, h1lo, packW, Abuf);
    mo_tile<<<dim3(4, 8, BDIM*CLS), 256, 0, stream>>>(Abuf, t1hi, t1lo, hk, tk, skp,
                                                      (float*)d_out);
}

// Round 2
// 199.518 us; speedup vs baseline: 1.0567x; 1.0265x over previous
//
#include <hip/hip_runtime.h>
#include <hip/hip_bf16.h>
#include <math.h>
#include <stdint.h>

#define BDIM 2
#define NDIM 512
#define HID 768
#define BIAF 256
#define CLS 14
#define DD 257   // BIAF+1
#define NPOS 30
#define SDIM 25
#define HSZ 539  // 2*257+25
#define PK 288   // padded contraction length (i and j), 9*32
#define PJ 384   // packW j-rows padding

typedef unsigned short ushort_t;
typedef __attribute__((ext_vector_type(8))) short short8;   // 8 bf16
typedef __attribute__((ext_vector_type(4))) float floatx4;  // 4 f32
typedef __attribute__((ext_vector_type(4))) unsigned short ushort4_t;

#define MFMA16(a, b, c) __builtin_amdgcn_mfma_f32_16x16x32_bf16((a), (b), (c), 0, 0, 0)

__device__ inline float bf2f(ushort_t u) {
    union { unsigned int i; float f; } c; c.i = ((unsigned)u) << 16; return c.f;
}
__device__ inline ushort_t f2bf(float f) {
    __hip_bfloat16 h = __float2bfloat16(f);
    return *(ushort_t*)&h;
}

// async global->LDS, 16B per lane. LDS dest = wave-uniform base + lane*16.
__device__ inline void glds16(const ushort_t* g, const ushort_t* l) {
    __builtin_amdgcn_global_load_lds(
        (const __attribute__((address_space(1))) unsigned int*)(unsigned long long)(uintptr_t)g,
        (__attribute__((address_space(3))) unsigned int*)(unsigned int)(uintptr_t)l,
        16, 0, 0);
}

// ---------------------------------------------------------------------------
// LDS swizzle (T2-style, rule #21 compliant: linear LDS dest, pre-swizzled
// global source, swizzled read address).
// Tile stored as [R][32] bf16 (64B rows). View row-pairs as 128B super-rows
// with eight 16B slots; slot' = slot ^ (super_row & 7).  8-lane read groups
// then cover all 32 banks (conflict-free b128).
// ---------------------------------------------------------------------------

// ---------------------------------------------------------------------------
// prep_all: fused repack_t (blocks 0..1511) + prep_split (blocks 1512..4327).
// repack: packW[k][j][i] = bf16(biafW[k][i][j]), zero-padded to PJ x PK.
// prep:   hi/lo bf16 splits of weights and x/y (float4-vectorized) + pads.
// ---------------------------------------------------------------------------
__global__ __launch_bounds__(256) void prep_all(
    const float* __restrict__ biafW, ushort_t* __restrict__ packW,
    const float* __restrict__ x, const float* __restrict__ y,
    const float* __restrict__ m1w, const float* __restrict__ m2w,
    const float* __restrict__ hw,  const float* __restrict__ tw,
    ushort_t* __restrict__ xhi, ushort_t* __restrict__ xlo,
    ushort_t* __restrict__ yhi, ushort_t* __restrict__ ylo,
    ushort_t* __restrict__ whi, ushort_t* __restrict__ wlo,
    ushort_t* __restrict__ h1hi, ushort_t* __restrict__ h1lo,
    ushort_t* __restrict__ t1hi, ushort_t* __restrict__ t1lo)
{
    const int bid = blockIdx.x;
    if (bid < 1512) {
        // ---- repack_t ----
        __shared__ float tile[32][33];
        const int ix = bid % 9;
        const int jy = (bid / 9) % 12;
        const int k  = bid / 108;
        const int i0 = ix * 32, j0 = jy * 32;
        const int r8 = threadIdx.x >> 5;   // 0..7
        const int c  = threadIdx.x & 31;
        #pragma unroll
        for (int rr = 0; rr < 4; ++rr) {
            int r = rr * 8 + r8;
            int gi = i0 + r, gj = j0 + c;
            tile[r][c] = (gi < DD && gj < DD) ? biafW[((size_t)k * DD + gi) * DD + gj] : 0.f;
        }
        __syncthreads();
        #pragma unroll
        for (int rr = 0; rr < 4; ++rr) {
            int jr = rr * 8 + r8;
            packW[((size_t)k * PJ + (j0 + jr)) * PK + i0 + c] = f2bf(tile[c][jr]);
        }
        return;
    }
    // ---- prep_split ----
    int tg = (bid - 1512) * 256 + threadIdx.x;
    if (tg < 196608) {
        // weights: 4 matrices x 196608 elems, 4 elems/thread
        int mat = tg / 49152;
        int e0  = (tg % 49152) * 4;
        const float* src = (mat == 0) ? m1w : (mat == 1) ? m2w : (mat == 2) ? hw : tw;
        float4 v = *(const float4*)(src + e0);
        size_t o = (size_t)mat * 196608 + e0;
        ushort4_t h, lo;
        h[0] = f2bf(v.x); lo[0] = f2bf(v.x - bf2f(h[0]));
        h[1] = f2bf(v.y); lo[1] = f2bf(v.y - bf2f(h[1]));
        h[2] = f2bf(v.z); lo[2] = f2bf(v.z - bf2f(h[2]));
        h[3] = f2bf(v.w); lo[3] = f2bf(v.w - bf2f(h[3]));
        *(ushort4_t*)(whi + o) = h;
        *(ushort4_t*)(wlo + o) = lo;
    } else if (tg < 589824) {
        // x and y: 786432 elems each, 4 elems/thread
        int t = tg - 196608;
        int which = t / 196608;
        int e0 = (t % 196608) * 4;
        const float* src = which ? y : x;
        float4 v = *(const float4*)(src + e0);
        ushort4_t h, lo;
        h[0] = f2bf(v.x); lo[0] = f2bf(v.x - bf2f(h[0]));
        h[1] = f2bf(v.y); lo[1] = f2bf(v.y - bf2f(h[1]));
        h[2] = f2bf(v.z); lo[2] = f2bf(v.z - bf2f(h[2]));
        h[3] = f2bf(v.w); lo[3] = f2bf(v.w - bf2f(h[3]));
        *(ushort4_t*)((which ? yhi : xhi) + e0) = h;
        *(ushort4_t*)((which ? ylo : xlo) + e0) = lo;
    } else {
        // pad columns of h1/t1 planes: col 256 = 1.0(hi)/0(lo), 257..287 = 0
        int idx = tg - 589824;                 // 0..131071
        int plane = idx >> 15;                 // 0..3
        int tok = (idx >> 5) & 1023;
        int c   = 256 + (idx & 31);
        ushort_t* dst = (plane == 0) ? h1hi : (plane == 1) ? h1lo : (plane == 2) ? t1hi : t1lo;
        ushort_t val = (c == 256 && (plane == 0 || plane == 2)) ? (ushort_t)0x3F80 : (ushort_t)0;
        dst[(size_t)tok * PK + c] = val;
    }
}

// ---------------------------------------------------------------------------
// proj_mfma v3: direct-load MFMA, pre-split operands, 3-term.
// grid (8 ft, 16 mt, 4 proj); wave tile = 16 tokens x 32 features.
// ---------------------------------------------------------------------------
__global__ __launch_bounds__(256) void proj_mfma(
    const ushort_t* __restrict__ xhi, const ushort_t* __restrict__ xlo,
    const ushort_t* __restrict__ yhi, const ushort_t* __restrict__ ylo,
    const ushort_t* __restrict__ whi, const ushort_t* __restrict__ wlo,
    const float* __restrict__ m1b, const float* __restrict__ m2b,
    const float* __restrict__ hb,  const float* __restrict__ tb,
    ushort_t* __restrict__ h1hi, ushort_t* __restrict__ h1lo,
    ushort_t* __restrict__ t1hi, ushort_t* __restrict__ t1lo,
    float* __restrict__ headf, float* __restrict__ tailf)
{
    const int ft = blockIdx.x;       // 0..7  -> 32 features
    const int mt = blockIdx.y;       // 0..15 -> 64 tokens
    const int proj = blockIdx.z;     // 0..3
    const int wave = threadIdx.x >> 6, L = threadIdx.x & 63;
    const int quad = L >> 4, l16 = L & 15;
    const int tok0 = mt * 64 + wave * 16;
    const int f0 = ft * 32;

    const ushort_t* ahi_p = (proj == 1) ? yhi : xhi;
    const ushort_t* alo_p = (proj == 1) ? ylo : xlo;
    const float* bias = (proj == 0) ? m1b : (proj == 1) ? m2b : (proj == 2) ? hb : tb;

    const size_t aoff = (size_t)(tok0 + l16) * HID + quad * 8;
    const size_t wbase = (size_t)proj * BIAF * HID;
    const size_t b0 = wbase + (size_t)(f0 + l16) * HID + quad * 8;
    const size_t b1 = wbase + (size_t)(f0 + 16 + l16) * HID + quad * 8;

    floatx4 acc0 = {0.f, 0.f, 0.f, 0.f}, acc1 = {0.f, 0.f, 0.f, 0.f};
    #pragma unroll 4
    for (int k0 = 0; k0 < HID; k0 += 32) {
        short8 ah  = *(const short8*)(ahi_p + aoff + k0);
        short8 al  = *(const short8*)(alo_p + aoff + k0);
        short8 bh0 = *(const short8*)(whi + b0 + k0);
        short8 bl0 = *(const short8*)(wlo + b0 + k0);
        short8 bh1 = *(const short8*)(whi + b1 + k0);
        short8 bl1 = *(const short8*)(wlo + b1 + k0);
        acc0 = MFMA16(ah, bh0, acc0);
        acc1 = MFMA16(ah, bh1, acc1);
        acc0 = MFMA16(al, bh0, acc0);
        acc1 = MFMA16(al, bh1, acc1);
        acc0 = MFMA16(ah, bl0, acc0);
        acc1 = MFMA16(ah, bl1, acc1);
    }

    #pragma unroll
    for (int nf = 0; nf < 2; ++nf) {
        floatx4 a = nf ? acc1 : acc0;
        int feat = f0 + nf * 16 + l16;
        float bv = bias[feat];
        #pragma unroll
        for (int r = 0; r < 4; ++r) {
            int tok = tok0 + quad * 4 + r;
            float v = a[r] + bv;
            if (proj <= 1) {
                float g = 0.5f * v * (1.0f + erff(v * 0.70710678118654752f));
                ushort_t h = f2bf(g);
                ushort_t lo = f2bf(g - bf2f(h));
                if (proj == 0) { h1hi[(size_t)tok * PK + feat] = h; h1lo[(size_t)tok * PK + feat] = lo; }
                else           { t1hi[(size_t)tok * PK + feat] = h; t1lo[(size_t)tok * PK + feat] = lo; }
            } else {
                float lv = (v >= 0.f) ? v : 0.01f * v;
                if (proj == 2) headf[(size_t)tok * 256 + feat] = lv;
                else           tailf[(size_t)tok * 256 + feat] = lv;
            }
        }
    }
}

// ---------------------------------------------------------------------------
// mb_hk: fused mb_tile (blocks 0..671) + hk_tk_sk (blocks 672..801).
// mb: A[bk][m][j] = sum_i h1[b][m][i] * biafW[k][i][j], 2-term on h1,
//     64x96 tile, double-buffered glds staging, XOR-swizzled LDS.
// hk: hk[b][k][m] = dot(headf, Wh[k]) + Wh[k][256]; tk likewise; sk small.
// ---------------------------------------------------------------------------
__global__ __launch_bounds__(256) void mb_hk(
    const ushort_t* __restrict__ h1hi, const ushort_t* __restrict__ h1lo,
    const ushort_t* __restrict__ packW,
    ushort_t* __restrict__ Ab,
    const float* __restrict__ headf, const float* __restrict__ tailf,
    const float* __restrict__ W, const float* __restrict__ semb,
    float* __restrict__ hk, float* __restrict__ tk, float* __restrict__ skp)
{
    const int bid = blockIdx.x;
    if (bid >= 672) {
        const int hb = bid - 672;           // 0..129
        if (hb >= 128) {
            int idx = (hb - 128) * 256 + threadIdx.x;
            if (idx < CLS * NPOS) {
                int k = idx / NPOS, d = idx % NPOS;
                float acc = 0.f;
                for (int h = 0; h < SDIM; ++h)
                    acc += semb[d*SDIM + h] * W[k*HSZ + 2*DD + h];
                skp[idx] = acc;
            }
            return;
        }
        int p = hb * 256 + threadIdx.x;      // 32768 items
        int which = p >> 14;                 // 0=hk, 1=tk
        int idx = p & 16383;
        int tok = idx >> 4;
        int k = idx & 15;
        if (k >= CLS) return;
        const float* row = (which ? tailf : headf) + (size_t)tok * 256;
        const float* wr = W + (size_t)k * HSZ + (which ? DD : 0);
        float acc = 0.f;
        for (int f4 = 0; f4 < 64; ++f4) {
            float4 rv = *(const float4*)(row + f4 * 4);
            acc += rv.x * wr[f4*4] + rv.y * wr[f4*4+1] + rv.z * wr[f4*4+2] + rv.w * wr[f4*4+3];
        }
        acc += wr[256];
        float* dst = which ? tk : hk;
        dst[(size_t)(tok >> 9) * CLS * NDIM + (size_t)k * NDIM + (tok & 511)] = acc;
        return;
    }

    // ---- mb_tile, double-buffered ----
    __shared__ ushort_t Ah[2 * 2048];   // 2 x 4KB
    __shared__ ushort_t Al[2 * 2048];   // 2 x 4KB
    __shared__ ushort_t Bt[2 * 3072];   // 2 x 6KB
    const int jt = bid % 3, mt = (bid / 3) % 8, bk = bid / 24;
    const int b = bk / CLS, k = bk % CLS;
    const int tid = threadIdx.x;
    const int wave = tid >> 6, L = tid & 63;
    const int quad = L >> 4, l16 = L & 15;
    // staging: lane L's linear LDS slot (sr=L>>3, sl=L&7) receives global
    // slot u = sl ^ sr  ->  global row 2*sr+(u>>2), col-quad u&3
    const int sr = L >> 3, u = (L & 7) ^ sr;
    const int srow = 2 * sr + (u >> 2);        // row within 16-row segment
    const int scol = (u & 3) * 8;              // element col within 32
    // read: fragment (row=base16+l16, quad) lives at swizzled slot
    const int rbase = (l16 >> 1) * 64 + ((((((l16 & 1) << 2) | quad)) ^ (l16 >> 1)) * 8);
    const int m0 = mt * 64, j0 = jt * 96;
    const int wm = (wave >> 1) * 32, wj = (wave & 1) * 48;

    const ushort_t* gAh = h1hi + (size_t)(b * NDIM + m0) * PK;
    const ushort_t* gAl = h1lo + (size_t)(b * NDIM + m0) * PK;
    const ushort_t* gB  = packW + ((size_t)k * PJ + j0) * PK;

    auto stage = [&](int bo, int k0) {
        for (int s = wave; s < 14; s += 4) {
            const ushort_t* g; const ushort_t* l;
            if (s < 4)      { l = Ah + bo * 2048 + s * 512;       g = gAh + (size_t)(s * 16 + srow) * PK + k0 + scol; }
            else if (s < 8) { l = Al + bo * 2048 + (s - 4) * 512; g = gAl + (size_t)((s - 4) * 16 + srow) * PK + k0 + scol; }
            else            { l = Bt + bo * 3072 + (s - 8) * 512; g = gB  + (size_t)((s - 8) * 16 + srow) * PK + k0 + scol; }
            glds16(g, l);
        }
    };

    floatx4 acc[2][3];
    #pragma unroll
    for (int mi = 0; mi < 2; ++mi)
        #pragma unroll
        for (int ni = 0; ni < 3; ++ni)
            #pragma unroll
            for (int r = 0; r < 4; ++r) acc[mi][ni][r] = 0.f;

    stage(0, 0);
    __syncthreads();
    int cur = 0;
    for (int t = 0; t < 9; ++t) {
        if (t < 8) stage(cur ^ 1, (t + 1) * 32);   // prefetch next tile
        short8 ah[2], al[2], bb[3];
        #pragma unroll
        for (int mi = 0; mi < 2; ++mi) {
            ah[mi] = *(const short8*)(Ah + cur * 2048 + (wm + mi * 16) * 32 + rbase);
            al[mi] = *(const short8*)(Al + cur * 2048 + (wm + mi * 16) * 32 + rbase);
        }
        #pragma unroll
        for (int ni = 0; ni < 3; ++ni)
            bb[ni] = *(const short8*)(Bt + cur * 3072 + (wj + ni * 16) * 32 + rbase);
        #pragma unroll
        for (int mi = 0; mi < 2; ++mi)
            #pragma unroll
            for (int ni = 0; ni < 3; ++ni) {
                acc[mi][ni] = MFMA16(ah[mi], bb[ni], acc[mi][ni]);
                acc[mi][ni] = MFMA16(al[mi], bb[ni], acc[mi][ni]);
            }
        __syncthreads();
        cur ^= 1;
    }

    ushort_t* Aout = Ab + (size_t)bk * NDIM * PK;
    #pragma unroll
    for (int mi = 0; mi < 2; ++mi) {
        #pragma unroll
        for (int r = 0; r < 4; ++r) {
            int row = m0 + wm + mi * 16 + quad * 4 + r;
            #pragma unroll
            for (int ni = 0; ni < 3; ++ni) {
                int col = j0 + wj + ni * 16 + l16;
                Aout[(size_t)row * PK + col] = f2bf(acc[mi][ni][r]);
            }
        }
    }
}

// ---------------------------------------------------------------------------
// mo_tile v5: out[bk][m][n] = sum_j A[bk][m][j]*t1[b][n][j] + hk + tk + sk
// tile 64x128, double-buffered glds staging, XOR-swizzled LDS.
// grid (4 nt, 8 mt, 28 bk) = 896 blocks.
// ---------------------------------------------------------------------------
__global__ __launch_bounds__(256) void mo_tile(
    const ushort_t* __restrict__ Ab,
    const ushort_t* __restrict__ t1hi, const ushort_t* __restrict__ t1lo,
    const float* __restrict__ hk, const float* __restrict__ tk,
    const float* __restrict__ sk,
    float* __restrict__ out)
{
    __shared__ ushort_t At[2 * 2048];    // 2 x 4KB
    __shared__ ushort_t Bh[2 * 4096];    // 2 x 8KB
    __shared__ ushort_t Bl[2 * 4096];    // 2 x 8KB
    __shared__ float skr[NPOS];
    const int nt = blockIdx.x, mt = blockIdx.y, bk = blockIdx.z;
    const int b = bk / CLS, k = bk % CLS;
    const int tid = threadIdx.x;
    if (tid < NPOS) skr[tid] = sk[k * NPOS + tid];
    const int wave = tid >> 6, L = tid & 63;
    const int quad = L >> 4, l16 = L & 15;
    const int sr = L >> 3, u = (L & 7) ^ sr;
    const int srow = 2 * sr + (u >> 2);
    const int scol = (u & 3) * 8;
    const int rbase = (l16 >> 1) * 64 + ((((((l16 & 1) << 2) | quad)) ^ (l16 >> 1)) * 8);
    const int m0 = mt * 64, n0 = nt * 128;
    const int wm = (wave >> 1) * 32, wn = (wave & 1) * 64;

    const ushort_t* gA  = Ab + ((size_t)bk * NDIM + m0) * PK;
    const ushort_t* gBh = t1hi + (size_t)(b * NDIM + n0) * PK;
    const ushort_t* gBl = t1lo + (size_t)(b * NDIM + n0) * PK;

    auto stage = [&](int bo, int k0) {
        for (int s = wave; s < 20; s += 4) {
            const ushort_t* g; const ushort_t* l;
            if (s < 4)       { l = At + bo * 2048 + s * 512;         g = gA  + (size_t)(s * 16 + srow) * PK + k0 + scol; }
            else if (s < 12) { l = Bh + bo * 4096 + (s - 4) * 512;   g = gBh + (size_t)((s - 4) * 16 + srow) * PK + k0 + scol; }
            else             { l = Bl + bo * 4096 + (s - 12) * 512;  g = gBl + (size_t)((s - 12) * 16 + srow) * PK + k0 + scol; }
            glds16(g, l);
        }
    };

    floatx4 acc[2][4];
    #pragma unroll
    for (int mi = 0; mi < 2; ++mi)
        #pragma unroll
        for (int ni = 0; ni < 4; ++ni)
            #pragma unroll
            for (int r = 0; r < 4; ++r) acc[mi][ni][r] = 0.f;

    stage(0, 0);
    __syncthreads();
    int cur = 0;
    for (int t = 0; t < 9; ++t) {
        if (t < 8) stage(cur ^ 1, (t + 1) * 32);   // prefetch next tile
        short8 a[2], bh[4], bl[4];
        #pragma unroll
        for (int mi = 0; mi < 2; ++mi)
            a[mi] = *(const short8*)(At + cur * 2048 + (wm + mi * 16) * 32 + rbase);
        #pragma unroll
        for (int ni = 0; ni < 4; ++ni) {
            bh[ni] = *(const short8*)(Bh + cur * 4096 + (wn + ni * 16) * 32 + rbase);
            bl[ni] = *(const short8*)(Bl + cur * 4096 + (wn + ni * 16) * 32 + rbase);
        }
        #pragma unroll
        for (int mi = 0; mi < 2; ++mi)
            #pragma unroll
            for (int ni = 0; ni < 4; ++ni) {
                acc[mi][ni] = MFMA16(a[mi], bh[ni], acc[mi][ni]);
                acc[mi][ni] = MFMA16(a[mi], bl[ni], acc[mi][ni]);
            }
        __syncthreads();
        cur ^= 1;
    }

    const size_t obase = (size_t)bk * NDIM;
    #pragma unroll
    for (int mi = 0; mi < 2; ++mi) {
        #pragma unroll
        for (int r = 0; r < 4; ++r) {
            int row = m0 + wm + mi * 16 + quad * 4 + r;
            float hv = hk[obase + row];
            #pragma unroll
            for (int ni = 0; ni < 4; ++ni) {
                int col = n0 + wn + ni * 16 + l16;
                int d = col - row; d = d < -15 ? -15 : (d > 14 ? 14 : d); d += 15;
                out[(obase + row) * NDIM + col] = acc[mi][ni][r] + hv + tk[obase + col] + skr[d];
            }
        }
    }
}

// ---------------------------------------------------------------------------
extern "C" void kernel_launch(void* const* d_in, const int* in_sizes, int n_in,
                              void* d_out, int out_size, void* d_ws, size_t ws_size,
                              hipStream_t stream) {
    const float* x    = (const float*)d_in[0];
    const float* y    = (const float*)d_in[1];
    // d_in[2] = z : unused
    const float* m1w  = (const float*)d_in[3];
    const float* m1b  = (const float*)d_in[4];
    const float* m2w  = (const float*)d_in[5];
    const float* m2b  = (const float*)d_in[6];
    const float* hw   = (const float*)d_in[7];
    const float* hb   = (const float*)d_in[8];
    const float* tw   = (const float*)d_in[9];
    const float* tb   = (const float*)d_in[10];
    const float* biafW= (const float*)d_in[11];
    const float* W    = (const float*)d_in[12];
    const float* semb = (const float*)d_in[13];

    char* p = (char*)d_ws;
    float* hk   = (float*)p;                    p += 57344;
    float* tk   = (float*)p;                    p += 57344;
    float* skp  = (float*)p;                    p += 2048;
    float* headf= (float*)p;                    p += 1048576;
    float* tailf= (float*)p;                    p += 1048576;
    ushort_t* h1hi = (ushort_t*)p;              p += 589824;
    ushort_t* h1lo = (ushort_t*)p;              p += 589824;
    ushort_t* t1hi = (ushort_t*)p;              p += 589824;
    ushort_t* t1lo = (ushort_t*)p;              p += 589824;
    ushort_t* packW= (ushort_t*)p;              p += 3096576;  // 14*384*288*2
    ushort_t* whi  = (ushort_t*)p;              p += 1572864;  // 4*256*768*2
    ushort_t* wlo  = (ushort_t*)p;              p += 1572864;
    ushort_t* Abuf = (ushort_t*)p;              p += 8257536;  // 28*512*288*2
    ushort_t* xhi  = (ushort_t*)p;              p += 1572864;  // 1024*768*2
    ushort_t* xlo  = (ushort_t*)p;              p += 1572864;
    ushort_t* yhi  = (ushort_t*)p;              p += 1572864;
    ushort_t* ylo  = (ushort_t*)p;              p += 1572864;

    prep_all<<<4328, 256, 0, stream>>>(biafW, packW, x, y, m1w, m2w, hw, tw,
                                       xhi, xlo, yhi, ylo, whi, wlo,
                                       h1hi, h1lo, t1hi, t1lo);
    proj_mfma<<<dim3(8, 16, 4), 256, 0, stream>>>(xhi, xlo, yhi, ylo, whi, wlo,
                                                  m1b, m2b, hb, tb,
                                                  h1hi, h1lo, t1hi, t1lo, headf, tailf);
    mb_hk<<<802, 256, 0, stream>>>(h1hi, h1lo, packW, Abuf,
                                   headf, tailf, W, semb, hk, tk, skp);
    mo_tile<<<dim3(4, 8, BDIM*CLS), 256, 0, stream>>>(Abuf, t1hi, t1lo, hk, tk, skp,
                                                      (float*)d_out);
}

// Round 3
// 198.323 us; speedup vs baseline: 1.0630x; 1.0060x over previous
//
#include <hip/hip_runtime.h>
#include <hip/hip_bf16.h>
#include <math.h>
#include <stdint.h>

#define BDIM 2
#define NDIM 512
#define HID 768
#define BIAF 256
#define CLS 14
#define DD 257   // BIAF+1
#define NPOS 30
#define SDIM 25
#define HSZ 539  // 2*257+25
#define PK 288   // padded contraction length (i and j), 9*32
#define PJ 384   // packW j-rows padding

typedef unsigned short ushort_t;
typedef __attribute__((ext_vector_type(8))) short short8;   // 8 bf16
typedef __attribute__((ext_vector_type(4))) float floatx4;  // 4 f32
typedef __attribute__((ext_vector_type(4))) unsigned short ushort4_t;

#define MFMA16(a, b, c) __builtin_amdgcn_mfma_f32_16x16x32_bf16((a), (b), (c), 0, 0, 0)

__device__ inline float bf2f(ushort_t u) {
    union { unsigned int i; float f; } c; c.i = ((unsigned)u) << 16; return c.f;
}
__device__ inline ushort_t f2bf(float f) {
    __hip_bfloat16 h = __float2bfloat16(f);
    return *(ushort_t*)&h;
}

// XCD-aware chunked swizzle (T1, bijective when nwg % 8 == 0): hardware
// round-robins dispatch index over 8 XCDs; this remap gives each XCD a
// CONTIGUOUS logical chunk so blocks sharing operand slices co-reside in
// one XCD's 4 MiB L2.
__device__ inline int xcd_swz(int bid, int nwg) {
    int q = nwg >> 3;                 // nwg/8, exact for all our grids
    return (bid & 7) * q + (bid >> 3);
}

// async global->LDS, 16B per lane. LDS dest = wave-uniform base + lane*16.
__device__ inline void glds16(const ushort_t* g, const ushort_t* l) {
    __builtin_amdgcn_global_load_lds(
        (const __attribute__((address_space(1))) unsigned int*)(unsigned long long)(uintptr_t)g,
        (__attribute__((address_space(3))) unsigned int*)(unsigned int)(uintptr_t)l,
        16, 0, 0);
}

// ---------------------------------------------------------------------------
// LDS swizzle (T2-style, rule #21 compliant: linear LDS dest, pre-swizzled
// global source, swizzled read address).
// Tile stored as [R][32] bf16 (64B rows). View row-pairs as 128B super-rows
// with eight 16B slots; slot' = slot ^ (super_row & 7).  8-lane read groups
// then cover all 32 banks (conflict-free b128).
// ---------------------------------------------------------------------------

// ---------------------------------------------------------------------------
// prep_all: fused repack_t (blocks 0..1511) + prep_split (blocks 1512..4327).
// repack: packW[k][j][i] = bf16(biafW[k][i][j]), zero-padded to PJ x PK.
// prep:   hi/lo bf16 splits of weights and x/y (float4-vectorized) + pads.
// ---------------------------------------------------------------------------
__global__ __launch_bounds__(256) void prep_all(
    const float* __restrict__ biafW, ushort_t* __restrict__ packW,
    const float* __restrict__ x, const float* __restrict__ y,
    const float* __restrict__ m1w, const float* __restrict__ m2w,
    const float* __restrict__ hw,  const float* __restrict__ tw,
    ushort_t* __restrict__ xhi, ushort_t* __restrict__ xlo,
    ushort_t* __restrict__ yhi, ushort_t* __restrict__ ylo,
    ushort_t* __restrict__ whi, ushort_t* __restrict__ wlo,
    ushort_t* __restrict__ h1hi, ushort_t* __restrict__ h1lo,
    ushort_t* __restrict__ t1hi, ushort_t* __restrict__ t1lo)
{
    const int bid = blockIdx.x;
    if (bid < 1512) {
        // ---- repack_t ----
        __shared__ float tile[32][33];
        const int ix = bid % 9;
        const int jy = (bid / 9) % 12;
        const int k  = bid / 108;
        const int i0 = ix * 32, j0 = jy * 32;
        const int r8 = threadIdx.x >> 5;   // 0..7
        const int c  = threadIdx.x & 31;
        #pragma unroll
        for (int rr = 0; rr < 4; ++rr) {
            int r = rr * 8 + r8;
            int gi = i0 + r, gj = j0 + c;
            tile[r][c] = (gi < DD && gj < DD) ? biafW[((size_t)k * DD + gi) * DD + gj] : 0.f;
        }
        __syncthreads();
        #pragma unroll
        for (int rr = 0; rr < 4; ++rr) {
            int jr = rr * 8 + r8;
            packW[((size_t)k * PJ + (j0 + jr)) * PK + i0 + c] = f2bf(tile[c][jr]);
        }
        return;
    }
    // ---- prep_split ----
    int tg = (bid - 1512) * 256 + threadIdx.x;
    if (tg < 196608) {
        // weights: 4 matrices x 196608 elems, 4 elems/thread
        int mat = tg / 49152;
        int e0  = (tg % 49152) * 4;
        const float* src = (mat == 0) ? m1w : (mat == 1) ? m2w : (mat == 2) ? hw : tw;
        float4 v = *(const float4*)(src + e0);
        size_t o = (size_t)mat * 196608 + e0;
        ushort4_t h, lo;
        h[0] = f2bf(v.x); lo[0] = f2bf(v.x - bf2f(h[0]));
        h[1] = f2bf(v.y); lo[1] = f2bf(v.y - bf2f(h[1]));
        h[2] = f2bf(v.z); lo[2] = f2bf(v.z - bf2f(h[2]));
        h[3] = f2bf(v.w); lo[3] = f2bf(v.w - bf2f(h[3]));
        *(ushort4_t*)(whi + o) = h;
        *(ushort4_t*)(wlo + o) = lo;
    } else if (tg < 589824) {
        // x and y: 786432 elems each, 4 elems/thread
        int t = tg - 196608;
        int which = t / 196608;
        int e0 = (t % 196608) * 4;
        const float* src = which ? y : x;
        float4 v = *(const float4*)(src + e0);
        ushort4_t h, lo;
        h[0] = f2bf(v.x); lo[0] = f2bf(v.x - bf2f(h[0]));
        h[1] = f2bf(v.y); lo[1] = f2bf(v.y - bf2f(h[1]));
        h[2] = f2bf(v.z); lo[2] = f2bf(v.z - bf2f(h[2]));
        h[3] = f2bf(v.w); lo[3] = f2bf(v.w - bf2f(h[3]));
        *(ushort4_t*)((which ? yhi : xhi) + e0) = h;
        *(ushort4_t*)((which ? ylo : xlo) + e0) = lo;
    } else {
        // pad columns of h1/t1 planes: col 256 = 1.0(hi)/0(lo), 257..287 = 0
        int idx = tg - 589824;                 // 0..131071
        int plane = idx >> 15;                 // 0..3
        int tok = (idx >> 5) & 1023;
        int c   = 256 + (idx & 31);
        ushort_t* dst = (plane == 0) ? h1hi : (plane == 1) ? h1lo : (plane == 2) ? t1hi : t1lo;
        ushort_t val = (c == 256 && (plane == 0 || plane == 2)) ? (ushort_t)0x3F80 : (ushort_t)0;
        dst[(size_t)tok * PK + c] = val;
    }
}

// ---------------------------------------------------------------------------
// proj_mfma v4: direct-load MFMA, pre-split operands, 3-term.
// 1D grid 512, XCD-swizzled: each XCD chunk = half a projection
// (weights 786KB + 8 activation tiles ~3.1MB -> fits 4MB per-XCD L2).
// wave tile = 16 tokens x 32 features.
// ---------------------------------------------------------------------------
__global__ __launch_bounds__(256) void proj_mfma(
    const ushort_t* __restrict__ xhi, const ushort_t* __restrict__ xlo,
    const ushort_t* __restrict__ yhi, const ushort_t* __restrict__ ylo,
    const ushort_t* __restrict__ whi, const ushort_t* __restrict__ wlo,
    const float* __restrict__ m1b, const float* __restrict__ m2b,
    const float* __restrict__ hb,  const float* __restrict__ tb,
    ushort_t* __restrict__ h1hi, ushort_t* __restrict__ h1lo,
    ushort_t* __restrict__ t1hi, ushort_t* __restrict__ t1lo,
    float* __restrict__ headf, float* __restrict__ tailf)
{
    const int flat = xcd_swz(blockIdx.x, 512);
    const int ft = flat & 7;         // 0..7  -> 32 features
    const int mt = (flat >> 3) & 15; // 0..15 -> 64 tokens
    const int proj = flat >> 7;      // 0..3
    const int wave = threadIdx.x >> 6, L = threadIdx.x & 63;
    const int quad = L >> 4, l16 = L & 15;
    const int tok0 = mt * 64 + wave * 16;
    const int f0 = ft * 32;

    const ushort_t* ahi_p = (proj == 1) ? yhi : xhi;
    const ushort_t* alo_p = (proj == 1) ? ylo : xlo;
    const float* bias = (proj == 0) ? m1b : (proj == 1) ? m2b : (proj == 2) ? hb : tb;

    const size_t aoff = (size_t)(tok0 + l16) * HID + quad * 8;
    const size_t wbase = (size_t)proj * BIAF * HID;
    const size_t b0 = wbase + (size_t)(f0 + l16) * HID + quad * 8;
    const size_t b1 = wbase + (size_t)(f0 + 16 + l16) * HID + quad * 8;

    floatx4 acc0 = {0.f, 0.f, 0.f, 0.f}, acc1 = {0.f, 0.f, 0.f, 0.f};
    #pragma unroll 4
    for (int k0 = 0; k0 < HID; k0 += 32) {
        short8 ah  = *(const short8*)(ahi_p + aoff + k0);
        short8 al  = *(const short8*)(alo_p + aoff + k0);
        short8 bh0 = *(const short8*)(whi + b0 + k0);
        short8 bl0 = *(const short8*)(wlo + b0 + k0);
        short8 bh1 = *(const short8*)(whi + b1 + k0);
        short8 bl1 = *(const short8*)(wlo + b1 + k0);
        acc0 = MFMA16(ah, bh0, acc0);
        acc1 = MFMA16(ah, bh1, acc1);
        acc0 = MFMA16(al, bh0, acc0);
        acc1 = MFMA16(al, bh1, acc1);
        acc0 = MFMA16(ah, bl0, acc0);
        acc1 = MFMA16(ah, bl1, acc1);
    }

    #pragma unroll
    for (int nf = 0; nf < 2; ++nf) {
        floatx4 a = nf ? acc1 : acc0;
        int feat = f0 + nf * 16 + l16;
        float bv = bias[feat];
        #pragma unroll
        for (int r = 0; r < 4; ++r) {
            int tok = tok0 + quad * 4 + r;
            float v = a[r] + bv;
            if (proj <= 1) {
                float g = 0.5f * v * (1.0f + erff(v * 0.70710678118654752f));
                ushort_t h = f2bf(g);
                ushort_t lo = f2bf(g - bf2f(h));
                if (proj == 0) { h1hi[(size_t)tok * PK + feat] = h; h1lo[(size_t)tok * PK + feat] = lo; }
                else           { t1hi[(size_t)tok * PK + feat] = h; t1lo[(size_t)tok * PK + feat] = lo; }
            } else {
                float lv = (v >= 0.f) ? v : 0.01f * v;
                if (proj == 2) headf[(size_t)tok * 256 + feat] = lv;
                else           tailf[(size_t)tok * 256 + feat] = lv;
            }
        }
    }
}

// ---------------------------------------------------------------------------
// mb_hk: fused mb_tile (blocks 0..671, XCD-swizzled) + hk_tk_sk (672..801).
// mb: A[bk][m][j] = sum_i h1[b][m][i] * biafW[k][i][j], 2-term on h1,
//     64x96 tile, double-buffered glds staging, XOR-swizzled LDS.
//     XCD chunk = 84 blocks = 3.5 bk-slabs (packW slice + h1 ~3MB, L2-fit).
// hk: hk[b][k][m] = dot(headf, Wh[k]) + Wh[k][256]; tk likewise; sk small.
// ---------------------------------------------------------------------------
__global__ __launch_bounds__(256) void mb_hk(
    const ushort_t* __restrict__ h1hi, const ushort_t* __restrict__ h1lo,
    const ushort_t* __restrict__ packW,
    ushort_t* __restrict__ Ab,
    const float* __restrict__ headf, const float* __restrict__ tailf,
    const float* __restrict__ W, const float* __restrict__ semb,
    float* __restrict__ hk, float* __restrict__ tk, float* __restrict__ skp)
{
    const int bid = blockIdx.x;
    if (bid >= 672) {
        const int hb = bid - 672;           // 0..129
        if (hb >= 128) {
            int idx = (hb - 128) * 256 + threadIdx.x;
            if (idx < CLS * NPOS) {
                int k = idx / NPOS, d = idx % NPOS;
                float acc = 0.f;
                for (int h = 0; h < SDIM; ++h)
                    acc += semb[d*SDIM + h] * W[k*HSZ + 2*DD + h];
                skp[idx] = acc;
            }
            return;
        }
        int p = hb * 256 + threadIdx.x;      // 32768 items
        int which = p >> 14;                 // 0=hk, 1=tk
        int idx = p & 16383;
        int tok = idx >> 4;
        int k = idx & 15;
        if (k >= CLS) return;
        const float* row = (which ? tailf : headf) + (size_t)tok * 256;
        const float* wr = W + (size_t)k * HSZ + (which ? DD : 0);
        float acc = 0.f;
        for (int f4 = 0; f4 < 64; ++f4) {
            float4 rv = *(const float4*)(row + f4 * 4);
            acc += rv.x * wr[f4*4] + rv.y * wr[f4*4+1] + rv.z * wr[f4*4+2] + rv.w * wr[f4*4+3];
        }
        acc += wr[256];
        float* dst = which ? tk : hk;
        dst[(size_t)(tok >> 9) * CLS * NDIM + (size_t)k * NDIM + (tok & 511)] = acc;
        return;
    }

    // ---- mb_tile, double-buffered, XCD-swizzled ----
    __shared__ ushort_t Ah[2 * 2048];   // 2 x 4KB
    __shared__ ushort_t Al[2 * 2048];   // 2 x 4KB
    __shared__ ushort_t Bt[2 * 3072];   // 2 x 6KB
    const int flat = xcd_swz(bid, 672);
    const int jt = flat % 3, mt = (flat / 3) % 8, bk = flat / 24;
    const int b = bk / CLS, k = bk % CLS;
    const int tid = threadIdx.x;
    const int wave = tid >> 6, L = tid & 63;
    const int quad = L >> 4, l16 = L & 15;
    // staging: lane L's linear LDS slot (sr=L>>3, sl=L&7) receives global
    // slot u = sl ^ sr  ->  global row 2*sr+(u>>2), col-quad u&3
    const int sr = L >> 3, u = (L & 7) ^ sr;
    const int srow = 2 * sr + (u >> 2);        // row within 16-row segment
    const int scol = (u & 3) * 8;              // element col within 32
    // read: fragment (row=base16+l16, quad) lives at swizzled slot
    const int rbase = (l16 >> 1) * 64 + ((((((l16 & 1) << 2) | quad)) ^ (l16 >> 1)) * 8);
    const int m0 = mt * 64, j0 = jt * 96;
    const int wm = (wave >> 1) * 32, wj = (wave & 1) * 48;

    const ushort_t* gAh = h1hi + (size_t)(b * NDIM + m0) * PK;
    const ushort_t* gAl = h1lo + (size_t)(b * NDIM + m0) * PK;
    const ushort_t* gB  = packW + ((size_t)k * PJ + j0) * PK;

    auto stage = [&](int bo, int k0) {
        for (int s = wave; s < 14; s += 4) {
            const ushort_t* g; const ushort_t* l;
            if (s < 4)      { l = Ah + bo * 2048 + s * 512;       g = gAh + (size_t)(s * 16 + srow) * PK + k0 + scol; }
            else if (s < 8) { l = Al + bo * 2048 + (s - 4) * 512; g = gAl + (size_t)((s - 4) * 16 + srow) * PK + k0 + scol; }
            else            { l = Bt + bo * 3072 + (s - 8) * 512; g = gB  + (size_t)((s - 8) * 16 + srow) * PK + k0 + scol; }
            glds16(g, l);
        }
    };

    floatx4 acc[2][3];
    #pragma unroll
    for (int mi = 0; mi < 2; ++mi)
        #pragma unroll
        for (int ni = 0; ni < 3; ++ni)
            #pragma unroll
            for (int r = 0; r < 4; ++r) acc[mi][ni][r] = 0.f;

    stage(0, 0);
    __syncthreads();
    int cur = 0;
    for (int t = 0; t < 9; ++t) {
        if (t < 8) stage(cur ^ 1, (t + 1) * 32);   // prefetch next tile
        short8 ah[2], al[2], bb[3];
        #pragma unroll
        for (int mi = 0; mi < 2; ++mi) {
            ah[mi] = *(const short8*)(Ah + cur * 2048 + (wm + mi * 16) * 32 + rbase);
            al[mi] = *(const short8*)(Al + cur * 2048 + (wm + mi * 16) * 32 + rbase);
        }
        #pragma unroll
        for (int ni = 0; ni < 3; ++ni)
            bb[ni] = *(const short8*)(Bt + cur * 3072 + (wj + ni * 16) * 32 + rbase);
        #pragma unroll
        for (int mi = 0; mi < 2; ++mi)
            #pragma unroll
            for (int ni = 0; ni < 3; ++ni) {
                acc[mi][ni] = MFMA16(ah[mi], bb[ni], acc[mi][ni]);
                acc[mi][ni] = MFMA16(al[mi], bb[ni], acc[mi][ni]);
            }
        __syncthreads();
        cur ^= 1;
    }

    ushort_t* Aout = Ab + (size_t)bk * NDIM * PK;
    #pragma unroll
    for (int mi = 0; mi < 2; ++mi) {
        #pragma unroll
        for (int r = 0; r < 4; ++r) {
            int row = m0 + wm + mi * 16 + quad * 4 + r;
            #pragma unroll
            for (int ni = 0; ni < 3; ++ni) {
                int col = j0 + wj + ni * 16 + l16;
                Aout[(size_t)row * PK + col] = f2bf(acc[mi][ni][r]);
            }
        }
    }
}

// ---------------------------------------------------------------------------
// mo_tile v6: out[bk][m][n] = sum_j A[bk][m][j]*t1[b][n][j] + hk + tk + sk
// tile 64x128, double-buffered glds staging, XOR-swizzled LDS.
// 1D grid 896, XCD-swizzled: chunk = 112 blocks = 3.5 bk-slabs
// (Abuf slice ~1MB + t1 2.4MB -> fits per-XCD L2; kills HBM re-reads).
// ---------------------------------------------------------------------------
__global__ __launch_bounds__(256) void mo_tile(
    const ushort_t* __restrict__ Ab,
    const ushort_t* __restrict__ t1hi, const ushort_t* __restrict__ t1lo,
    const float* __restrict__ hk, const float* __restrict__ tk,
    const float* __restrict__ sk,
    float* __restrict__ out)
{
    __shared__ ushort_t At[2 * 2048];    // 2 x 4KB
    __shared__ ushort_t Bh[2 * 4096];    // 2 x 8KB
    __shared__ ushort_t Bl[2 * 4096];    // 2 x 8KB
    __shared__ float skr[NPOS];
    const int flat = xcd_swz(blockIdx.x, 896);
    const int nt = flat & 3, mt = (flat >> 2) & 7, bk = flat >> 5;
    const int b = bk / CLS, k = bk % CLS;
    const int tid = threadIdx.x;
    if (tid < NPOS) skr[tid] = sk[k * NPOS + tid];
    const int wave = tid >> 6, L = tid & 63;
    const int quad = L >> 4, l16 = L & 15;
    const int sr = L >> 3, u = (L & 7) ^ sr;
    const int srow = 2 * sr + (u >> 2);
    const int scol = (u & 3) * 8;
    const int rbase = (l16 >> 1) * 64 + ((((((l16 & 1) << 2) | quad)) ^ (l16 >> 1)) * 8);
    const int m0 = mt * 64, n0 = nt * 128;
    const int wm = (wave >> 1) * 32, wn = (wave & 1) * 64;

    const ushort_t* gA  = Ab + ((size_t)bk * NDIM + m0) * PK;
    const ushort_t* gBh = t1hi + (size_t)(b * NDIM + n0) * PK;
    const ushort_t* gBl = t1lo + (size_t)(b * NDIM + n0) * PK;

    auto stage = [&](int bo, int k0) {
        for (int s = wave; s < 20; s += 4) {
            const ushort_t* g; const ushort_t* l;
            if (s < 4)       { l = At + bo * 2048 + s * 512;         g = gA  + (size_t)(s * 16 + srow) * PK + k0 + scol; }
            else if (s < 12) { l = Bh + bo * 4096 + (s - 4) * 512;   g = gBh + (size_t)((s - 4) * 16 + srow) * PK + k0 + scol; }
            else             { l = Bl + bo * 4096 + (s - 12) * 512;  g = gBl + (size_t)((s - 12) * 16 + srow) * PK + k0 + scol; }
            glds16(g, l);
        }
    };

    floatx4 acc[2][4];
    #pragma unroll
    for (int mi = 0; mi < 2; ++mi)
        #pragma unroll
        for (int ni = 0; ni < 4; ++ni)
            #pragma unroll
            for (int r = 0; r < 4; ++r) acc[mi][ni][r] = 0.f;

    stage(0, 0);
    __syncthreads();
    int cur = 0;
    for (int t = 0; t < 9; ++t) {
        if (t < 8) stage(cur ^ 1, (t + 1) * 32);   // prefetch next tile
        short8 a[2], bh[4], bl[4];
        #pragma unroll
        for (int mi = 0; mi < 2; ++mi)
            a[mi] = *(const short8*)(At + cur * 2048 + (wm + mi * 16) * 32 + rbase);
        #pragma unroll
        for (int ni = 0; ni < 4; ++ni) {
            bh[ni] = *(const short8*)(Bh + cur * 4096 + (wn + ni * 16) * 32 + rbase);
            bl[ni] = *(const short8*)(Bl + cur * 4096 + (wn + ni * 16) * 32 + rbase);
        }
        #pragma unroll
        for (int mi = 0; mi < 2; ++mi)
            #pragma unroll
            for (int ni = 0; ni < 4; ++ni) {
                acc[mi][ni] = MFMA16(a[mi], bh[ni], acc[mi][ni]);
                acc[mi][ni] = MFMA16(a[mi], bl[ni], acc[mi][ni]);
            }
        __syncthreads();
        cur ^= 1;
    }

    const size_t obase = (size_t)bk * NDIM;
    #pragma unroll
    for (int mi = 0; mi < 2; ++mi) {
        #pragma unroll
        for (int r = 0; r < 4; ++r) {
            int row = m0 + wm + mi * 16 + quad * 4 + r;
            float hv = hk[obase + row];
            #pragma unroll
            for (int ni = 0; ni < 4; ++ni) {
                int col = n0 + wn + ni * 16 + l16;
                int d = col - row; d = d < -15 ? -15 : (d > 14 ? 14 : d); d += 15;
                out[(obase + row) * NDIM + col] = acc[mi][ni][r] + hv + tk[obase + col] + skr[d];
            }
        }
    }
}

// ---------------------------------------------------------------------------
extern "C" void kernel_launch(void* const* d_in, const int* in_sizes, int n_in,
                              void* d_out, int out_size, void* d_ws, size_t ws_size,
                              hipStream_t stream) {
    const float* x    = (const float*)d_in[0];
    const float* y    = (const float*)d_in[1];
    // d_in[2] = z : unused
    const float* m1w  = (const float*)d_in[3];
    const float* m1b  = (const float*)d_in[4];
    const float* m2w  = (const float*)d_in[5];
    const float* m2b  = (const float*)d_in[6];
    const float* hw   = (const float*)d_in[7];
    const float* hb   = (const float*)d_in[8];
    const float* tw   = (const float*)d_in[9];
    const float* tb   = (const float*)d_in[10];
    const float* biafW= (const float*)d_in[11];
    const float* W    = (const float*)d_in[12];
    const float* semb = (const float*)d_in[13];

    char* p = (char*)d_ws;
    float* hk   = (float*)p;                    p += 57344;
    float* tk   = (float*)p;                    p += 57344;
    float* skp  = (float*)p;                    p += 2048;
    float* headf= (float*)p;                    p += 1048576;
    float* tailf= (float*)p;                    p += 1048576;
    ushort_t* h1hi = (ushort_t*)p;              p += 589824;
    ushort_t* h1lo = (ushort_t*)p;              p += 589824;
    ushort_t* t1hi = (ushort_t*)p;              p += 589824;
    ushort_t* t1lo = (ushort_t*)p;              p += 589824;
    ushort_t* packW= (ushort_t*)p;              p += 3096576;  // 14*384*288*2
    ushort_t* whi  = (ushort_t*)p;              p += 1572864;  // 4*256*768*2
    ushort_t* wlo  = (ushort_t*)p;              p += 1572864;
    ushort_t* Abuf = (ushort_t*)p;              p += 8257536;  // 28*512*288*2
    ushort_t* xhi  = (ushort_t*)p;              p += 1572864;  // 1024*768*2
    ushort_t* xlo  = (ushort_t*)p;              p += 1572864;
    ushort_t* yhi  = (ushort_t*)p;              p += 1572864;
    ushort_t* ylo  = (ushort_t*)p;              p += 1572864;

    prep_all<<<4328, 256, 0, stream>>>(biafW, packW, x, y, m1w, m2w, hw, tw,
                                       xhi, xlo, yhi, ylo, whi, wlo,
                                       h1hi, h1lo, t1hi, t1lo);
    proj_mfma<<<512, 256, 0, stream>>>(xhi, xlo, yhi, ylo, whi, wlo,
                                       m1b, m2b, hb, tb,
                                       h1hi, h1lo, t1hi, t1lo, headf, tailf);
    mb_hk<<<802, 256, 0, stream>>>(h1hi, h1lo, packW, Abuf,
                                   headf, tailf, W, semb, hk, tk, skp);
    mo_tile<<<896, 256, 0, stream>>>(Abuf, t1hi, t1lo, hk, tk, skp,
                                     (float*)d_out);
}